// Round 1
// baseline (330.545 us; speedup 1.0000x reference)
//
#include <hip/hip_runtime.h>

// Problem constants (fixed by harness)
#define NPG 96                  // nodes per graph
#define BGR 64                  // graphs
#define HID 64
#define INF 32
#define EF  16
#define DEG 8
#define NN  (BGR*NPG)           // 6144 nodes
#define NE  (BGR*NPG*DEG)       // 49152 edges
#define EPG (NPG*DEG)           // 768 edges per graph
#define PPG (NPG*NPG)           // 9216 pairs per graph
#define ROWS_PER_TILE 4
#define TILES_PER_G (NPG/ROWS_PER_TILE)   // 24
#define TPB3 (ROWS_PER_TILE*NPG)          // 384 threads (6 waves)

// ---------------------------------------------------------------------------
// K1: per-node  A = ((x@Wa+ba)@Wn+bn)@W1[0:64],  B = same @ W1[64:128]
// one node per wave; lane = output channel c. x-row reads are wave-uniform
// (readfirstlane forces s_load); weight reads are lane-coalesced.
// ---------------------------------------------------------------------------
__global__ __launch_bounds__(256) void node_kernel(
    const float* __restrict__ x,
    const float* __restrict__ W_atom, const float* __restrict__ b_atom,
    const float* __restrict__ W_node, const float* __restrict__ b_node,
    const float* __restrict__ W1,
    float* __restrict__ Abuf, float* __restrict__ Bbuf)
{
    __shared__ float sh[4][64];
    const int wave = threadIdx.x >> 6, lane = threadIdx.x & 63;
    const int n = __builtin_amdgcn_readfirstlane(blockIdx.x * 4 + wave);
    const float* xr = x + n * INF;

    float xh = b_atom[lane];
    #pragma unroll
    for (int k = 0; k < INF; ++k) xh += xr[k] * W_atom[k*HID + lane];
    sh[wave][lane] = xh;
    __syncthreads();

    float en = b_node[lane];
    #pragma unroll
    for (int k = 0; k < HID; ++k) en += sh[wave][k] * W_node[k*HID + lane];
    __syncthreads();
    sh[wave][lane] = en;
    __syncthreads();

    float a = 0.f, b = 0.f;
    #pragma unroll
    for (int k = 0; k < HID; ++k) {
        const float ek = sh[wave][k];
        a += ek * W1[k*HID + lane];
        b += ek * W1[(HID + k)*HID + lane];
    }
    Abuf[n*HID + lane] = a;
    Bbuf[n*HID + lane] = b;
}

// ---------------------------------------------------------------------------
// K2: per-edge  c_e = ((ea@Wb+bb)@We+be)@W1[128:192]   (bias of emb_e included
// per edge, matching reference scatter-add of emb_e). One edge per wave.
// ---------------------------------------------------------------------------
__global__ __launch_bounds__(256) void edge_kernel(
    const float* __restrict__ ea,
    const float* __restrict__ W_bond, const float* __restrict__ b_bond,
    const float* __restrict__ W_edge, const float* __restrict__ b_edge,
    const float* __restrict__ W1,
    float* __restrict__ CE)
{
    __shared__ float sh[4][64];
    const int wave = threadIdx.x >> 6, lane = threadIdx.x & 63;
    const int e = __builtin_amdgcn_readfirstlane(blockIdx.x * 4 + wave);
    const float* er = ea + e * EF;

    float eh = b_bond[lane];
    #pragma unroll
    for (int k = 0; k < EF; ++k) eh += er[k] * W_bond[k*HID + lane];
    sh[wave][lane] = eh;
    __syncthreads();

    float ee = b_edge[lane];
    #pragma unroll
    for (int k = 0; k < HID; ++k) ee += sh[wave][k] * W_edge[k*HID + lane];
    __syncthreads();
    sh[wave][lane] = ee;
    __syncthreads();

    float ce = 0.f;
    #pragma unroll
    for (int k = 0; k < HID; ++k) ce += sh[wave][k] * W1[(2*HID + k)*HID + lane];
    CE[e*HID + lane] = ce;
}

// ---------------------------------------------------------------------------
// K3: per-pair MLP, fused. Block = (graph, 4-row tile) = 384 pairs, one pair
// per thread. Sparse edge contributions accumulated into LDS tile (stride 65
// to kill bank conflicts). h1 built scalar-per-k inside the W2 loop (no h1
// register array). W2/b1/b2/w3 reads are wave-uniform -> s_load from K$.
// ---------------------------------------------------------------------------
__global__ __launch_bounds__(TPB3) void pair_kernel(
    const float* __restrict__ Abuf, const float* __restrict__ Bbuf,
    const float* __restrict__ CE,   const int* __restrict__ eidx,
    const float* __restrict__ b1,
    const float* __restrict__ W2,   const float* __restrict__ b2,
    const float* __restrict__ W3,   const float* __restrict__ b3,
    float* __restrict__ out)
{
    __shared__ float sS[TPB3 * 65];          // 99840 B  pair tile (h1 sparse part)
    __shared__ float sB[NPG * 65];           // 24960 B  B rows for all 96 cols
    __shared__ float sA[ROWS_PER_TILE * 64]; //  1024 B  A rows for the 4 tile rows
    const int t = threadIdx.x;
    const int g    = blockIdx.x / TILES_PER_G;
    const int tile = blockIdx.x % TILES_PER_G;
    const int i0   = tile * ROWS_PER_TILE;

    // ---- stage ----
    for (int idx = t; idx < NPG*64; idx += TPB3)
        sB[(idx >> 6)*65 + (idx & 63)] = Bbuf[g*NPG*64 + idx];
    for (int idx = t; idx < ROWS_PER_TILE*64; idx += TPB3)
        sA[idx] = Abuf[(g*NPG + i0)*64 + idx];
    for (int idx = t; idx < TPB3*65; idx += TPB3)
        sS[idx] = 0.f;
    __syncthreads();

    // ---- scatter this graph's edges into the row tile ----
    const int gbase = g * EPG;
    for (int idx = t; idx < EPG*8; idx += TPB3) {
        const int e  = idx >> 3;
        const int kc = (idx & 7) * 8;
        const int u  = eidx[gbase + e];
        const int li = u - g*NPG - i0;
        if (li >= 0 && li < ROWS_PER_TILE) {
            const int v = eidx[NE + gbase + e];
            const int j = v - g*NPG;
            const float* ce = CE + (gbase + e)*64 + kc;
            float* dst = sS + (li*NPG + j)*65 + kc;
            #pragma unroll
            for (int kk = 0; kk < 8; ++kk) atomicAdd(dst + kk, ce[kk]);
        }
    }
    __syncthreads();

    // ---- per-pair MLP: h1 -> h2 -> out ----
    const int li = t / NPG, j = t % NPG;
    float h2[64];
    #pragma unroll
    for (int c = 0; c < 64; ++c) h2[c] = b2[c];

    const float* sSrow = sS + t*65;
    const float* sBrow = sB + j*65;
    const float* sArow = sA + li*64;

    for (int k = 0; k < 64; ++k) {
        float h1 = sArow[k] + sBrow[k] + sSrow[k] + b1[k];
        h1 = fmaxf(h1, 0.f);
        const float4* wrow = (const float4*)(W2 + k*64);
        #pragma unroll
        for (int c4 = 0; c4 < 16; ++c4) {
            const float4 w = wrow[c4];
            h2[c4*4+0] += h1 * w.x;
            h2[c4*4+1] += h1 * w.y;
            h2[c4*4+2] += h1 * w.z;
            h2[c4*4+3] += h1 * w.w;
        }
    }

    float acc = b3[0];
    #pragma unroll
    for (int c = 0; c < 64; ++c) acc += fmaxf(h2[c], 0.f) * W3[c];
    out[g*PPG + (i0 + li)*NPG + j] = acc;
}

// ---------------------------------------------------------------------------
extern "C" void kernel_launch(void* const* d_in, const int* in_sizes, int n_in,
                              void* d_out, int out_size, void* d_ws, size_t ws_size,
                              hipStream_t stream)
{
    const float* x      = (const float*)d_in[0];
    const float* ea     = (const float*)d_in[1];
    const int*   eidx   = (const int*)  d_in[2];
    // d_in[3]=idx0, d_in[4]=idx1, d_in[5]=n  -- derivable, unused
    const float* W_atom = (const float*)d_in[6];
    const float* b_atom = (const float*)d_in[7];
    const float* W_bond = (const float*)d_in[8];
    const float* b_bond = (const float*)d_in[9];
    const float* W_node = (const float*)d_in[10];
    const float* b_node = (const float*)d_in[11];
    const float* W_edge = (const float*)d_in[12];
    const float* b_edge = (const float*)d_in[13];
    const float* W1     = (const float*)d_in[14];
    const float* b1     = (const float*)d_in[15];
    const float* W2     = (const float*)d_in[16];
    const float* b2     = (const float*)d_in[17];
    const float* W3     = (const float*)d_in[18];
    const float* b3     = (const float*)d_in[19];
    float* out = (float*)d_out;

    float* ws   = (float*)d_ws;          // needs 15.7 MB
    float* Abuf = ws;                    // [NN,64]
    float* Bbuf = ws + NN*HID;           // [NN,64]
    float* CE   = ws + 2*NN*HID;         // [NE,64]

    node_kernel<<<NN/4, 256, 0, stream>>>(x, W_atom, b_atom, W_node, b_node, W1, Abuf, Bbuf);
    edge_kernel<<<NE/4, 256, 0, stream>>>(ea, W_bond, b_bond, W_edge, b_edge, W1, CE);
    pair_kernel<<<BGR*TILES_PER_G, TPB3, 0, stream>>>(Abuf, Bbuf, CE, eidx,
                                                      b1, W2, b2, W3, b3, out);
}

// Round 2
// 284.260 us; speedup vs baseline: 1.1628x; 1.1628x over previous
//
#include <hip/hip_runtime.h>

// Problem constants (fixed by harness)
#define NPG 96                  // nodes per graph
#define BGR 64                  // graphs
#define HID 64
#define INF 32
#define EF  16
#define DEG 8
#define NN  (BGR*NPG)           // 6144 nodes
#define NE  (BGR*NPG*DEG)       // 49152 edges
#define EPG (NPG*DEG)           // 768 edges per graph
#define PPG (NPG*NPG)           // 9216 pairs per graph

// ---------------------------------------------------------------------------
// K1: per-node  A = ((x@Wa+ba)@Wn+bn)@W1[0:64] + b1   (b1 folded into A),
//               B = same @ W1[64:128]
// one node per wave; lane = output channel c.
// ---------------------------------------------------------------------------
__global__ __launch_bounds__(256) void node_kernel(
    const float* __restrict__ x,
    const float* __restrict__ W_atom, const float* __restrict__ b_atom,
    const float* __restrict__ W_node, const float* __restrict__ b_node,
    const float* __restrict__ W1,     const float* __restrict__ b1,
    float* __restrict__ Abuf, float* __restrict__ Bbuf)
{
    __shared__ float sh[4][64];
    const int wave = threadIdx.x >> 6, lane = threadIdx.x & 63;
    const int n = __builtin_amdgcn_readfirstlane(blockIdx.x * 4 + wave);
    const float* xr = x + n * INF;

    float xh = b_atom[lane];
    #pragma unroll
    for (int k = 0; k < INF; ++k) xh += xr[k] * W_atom[k*HID + lane];
    sh[wave][lane] = xh;
    __syncthreads();

    float en = b_node[lane];
    #pragma unroll
    for (int k = 0; k < HID; ++k) en += sh[wave][k] * W_node[k*HID + lane];
    __syncthreads();
    sh[wave][lane] = en;
    __syncthreads();

    float a = b1[lane], b = 0.f;
    #pragma unroll
    for (int k = 0; k < HID; ++k) {
        const float ek = sh[wave][k];
        a += ek * W1[k*HID + lane];
        b += ek * W1[(HID + k)*HID + lane];
    }
    Abuf[n*HID + lane] = a;
    Bbuf[n*HID + lane] = b;
}

// ---------------------------------------------------------------------------
// K2: per-edge  c_e = ((ea@Wb+bb)@We+be)@W1[128:192]
// ---------------------------------------------------------------------------
__global__ __launch_bounds__(256) void edge_kernel(
    const float* __restrict__ ea,
    const float* __restrict__ W_bond, const float* __restrict__ b_bond,
    const float* __restrict__ W_edge, const float* __restrict__ b_edge,
    const float* __restrict__ W1,
    float* __restrict__ CE)
{
    __shared__ float sh[4][64];
    const int wave = threadIdx.x >> 6, lane = threadIdx.x & 63;
    const int e = __builtin_amdgcn_readfirstlane(blockIdx.x * 4 + wave);
    const float* er = ea + e * EF;

    float eh = b_bond[lane];
    #pragma unroll
    for (int k = 0; k < EF; ++k) eh += er[k] * W_bond[k*HID + lane];
    sh[wave][lane] = eh;
    __syncthreads();

    float ee = b_edge[lane];
    #pragma unroll
    for (int k = 0; k < HID; ++k) ee += sh[wave][k] * W_edge[k*HID + lane];
    __syncthreads();
    sh[wave][lane] = ee;
    __syncthreads();

    float ce = 0.f;
    #pragma unroll
    for (int k = 0; k < HID; ++k) ce += sh[wave][k] * W1[(2*HID + k)*HID + lane];
    CE[e*HID + lane] = ce;
}

// ---------------------------------------------------------------------------
// K3: dense pair MLP assuming NO sparse contribution:
//     out(i,j) = w3 . relu(W2^T relu(A'[i]+B[j]) + b2) + b3
// 256 consecutive pairs per block. LDS = 96 B-rows (stride 65) + 4 A-rows
// ~26 KB -> 5 blocks/CU (VGPR-capped), 62% occupancy.
// Edge-pairs get wrong values here; K4 overwrites them.
// ---------------------------------------------------------------------------
__global__ __launch_bounds__(256, 5) void pair_dense_kernel(
    const float* __restrict__ Abuf, const float* __restrict__ Bbuf,
    const float* __restrict__ W2,   const float* __restrict__ b2,
    const float* __restrict__ W3,   const float* __restrict__ b3,
    float* __restrict__ out)
{
    __shared__ float sB[NPG * 65];
    __shared__ float sA[4 * 64];
    const int t  = threadIdx.x;
    const int p0 = blockIdx.x * 256;
    const int g  = p0 / PPG;
    const int l0 = p0 % PPG;
    const int i0 = l0 / NPG;

    const float* Bg = Bbuf + g * NPG * 64;
    for (int idx = t; idx < NPG*64; idx += 256)
        sB[(idx >> 6)*65 + (idx & 63)] = Bg[idx];
    {   // 4 A-rows (i0..i0+3), clamped
        const int i = i0 + (t >> 6);
        sA[t] = (i < NPG) ? Abuf[(g*NPG + i)*64 + (t & 63)] : 0.f;
    }
    __syncthreads();

    const int l = l0 + t;
    const int i = l / NPG, j = l % NPG;
    const float* sArow = sA + (i - i0)*64;
    const float* sBrow = sB + j*65;

    float h2[64];
    #pragma unroll
    for (int c = 0; c < 64; ++c) h2[c] = b2[c];

    for (int k = 0; k < 64; ++k) {
        float h1 = sArow[k] + sBrow[k];
        h1 = fmaxf(h1, 0.f);
        const float4* wrow = (const float4*)(W2 + k*64);
        #pragma unroll
        for (int c4 = 0; c4 < 16; ++c4) {
            const float4 w = wrow[c4];
            h2[c4*4+0] += h1 * w.x;
            h2[c4*4+1] += h1 * w.y;
            h2[c4*4+2] += h1 * w.z;
            h2[c4*4+3] += h1 * w.w;
        }
    }

    float acc = b3[0];
    #pragma unroll
    for (int c = 0; c < 64; ++c) acc += fmaxf(h2[c], 0.f) * W3[c];
    out[p0 + t] = acc;
}

// ---------------------------------------------------------------------------
// K4: correction for pairs that have >=1 edge. One block per graph, one
// thread per edge. Duplicate (i,j) edges deduped via LDS linked list
// (atomicExch); the chain head recomputes the full MLP including the sparse
// sum and overwrites out. Runs AFTER K3 on the stream.
// ---------------------------------------------------------------------------
__global__ __launch_bounds__(EPG) void pair_fix_kernel(
    const float* __restrict__ Abuf, const float* __restrict__ Bbuf,
    const float* __restrict__ CE,   const int* __restrict__ eidx,
    const float* __restrict__ W2,   const float* __restrict__ b2,
    const float* __restrict__ W3,   const float* __restrict__ b3,
    float* __restrict__ out)
{
    __shared__ int   head[PPG];       // 36864 B
    __shared__ int   nxt[EPG];        //  3072 B
    __shared__ float sA[NPG * 65];    // 24960 B
    __shared__ float sB[NPG * 65];    // 24960 B
    const int t = threadIdx.x;
    const int g = blockIdx.x;

    for (int idx = t; idx < PPG; idx += EPG) head[idx] = -1;
    const float* Ag = Abuf + g*NPG*64;
    const float* Bg = Bbuf + g*NPG*64;
    for (int idx = t; idx < NPG*64; idx += EPG) {
        sA[(idx >> 6)*65 + (idx & 63)] = Ag[idx];
        sB[(idx >> 6)*65 + (idx & 63)] = Bg[idx];
    }
    const int u = eidx[g*EPG + t]      - g*NPG;   // src -> row i
    const int v = eidx[NE + g*EPG + t] - g*NPG;   // dst -> col j
    const int key = u*NPG + v;
    __syncthreads();

    nxt[t] = atomicExch(&head[key], t);
    __syncthreads();

    if (head[key] == t) {   // chain owner
        float h2[64];
        #pragma unroll
        for (int c = 0; c < 64; ++c) h2[c] = b2[c];

        const float* sArow = sA + u*65;
        const float* sBrow = sB + v*65;

        #pragma unroll
        for (int half = 0; half < 2; ++half) {
            float s[32];
            #pragma unroll
            for (int q = 0; q < 32; ++q) s[q] = 0.f;
            for (int e = t; e != -1; e = nxt[e]) {
                const float4* cr = (const float4*)(CE + (g*EPG + e)*64 + half*32);
                #pragma unroll
                for (int q = 0; q < 8; ++q) {
                    const float4 c4 = cr[q];
                    s[q*4+0] += c4.x; s[q*4+1] += c4.y;
                    s[q*4+2] += c4.z; s[q*4+3] += c4.w;
                }
            }
            #pragma unroll
            for (int kk = 0; kk < 32; ++kk) {
                const int k = half*32 + kk;
                float h1 = sArow[k] + sBrow[k] + s[kk];
                h1 = fmaxf(h1, 0.f);
                const float4* wrow = (const float4*)(W2 + k*64);
                #pragma unroll
                for (int c4i = 0; c4i < 16; ++c4i) {
                    const float4 w = wrow[c4i];
                    h2[c4i*4+0] += h1 * w.x;
                    h2[c4i*4+1] += h1 * w.y;
                    h2[c4i*4+2] += h1 * w.z;
                    h2[c4i*4+3] += h1 * w.w;
                }
            }
        }

        float acc = b3[0];
        #pragma unroll
        for (int c = 0; c < 64; ++c) acc += fmaxf(h2[c], 0.f) * W3[c];
        out[g*PPG + key] = acc;
    }
}

// ---------------------------------------------------------------------------
extern "C" void kernel_launch(void* const* d_in, const int* in_sizes, int n_in,
                              void* d_out, int out_size, void* d_ws, size_t ws_size,
                              hipStream_t stream)
{
    const float* x      = (const float*)d_in[0];
    const float* ea     = (const float*)d_in[1];
    const int*   eidx   = (const int*)  d_in[2];
    // d_in[3]=idx0, d_in[4]=idx1, d_in[5]=n  -- derivable, unused
    const float* W_atom = (const float*)d_in[6];
    const float* b_atom = (const float*)d_in[7];
    const float* W_bond = (const float*)d_in[8];
    const float* b_bond = (const float*)d_in[9];
    const float* W_node = (const float*)d_in[10];
    const float* b_node = (const float*)d_in[11];
    const float* W_edge = (const float*)d_in[12];
    const float* b_edge = (const float*)d_in[13];
    const float* W1     = (const float*)d_in[14];
    const float* b1     = (const float*)d_in[15];
    const float* W2     = (const float*)d_in[16];
    const float* b2     = (const float*)d_in[17];
    const float* W3     = (const float*)d_in[18];
    const float* b3     = (const float*)d_in[19];
    float* out = (float*)d_out;

    float* ws   = (float*)d_ws;
    float* Abuf = ws;                    // [NN,64]  1.5 MB
    float* Bbuf = ws + NN*HID;           // [NN,64]  1.5 MB
    float* CE   = ws + 2*NN*HID;         // [NE,64] 12.6 MB

    node_kernel<<<NN/4, 256, 0, stream>>>(x, W_atom, b_atom, W_node, b_node,
                                          W1, b1, Abuf, Bbuf);
    edge_kernel<<<NE/4, 256, 0, stream>>>(ea, W_bond, b_bond, W_edge, b_edge,
                                          W1, CE);
    pair_dense_kernel<<<(BGR*PPG)/256, 256, 0, stream>>>(Abuf, Bbuf,
                                                         W2, b2, W3, b3, out);
    pair_fix_kernel<<<BGR, EPG, 0, stream>>>(Abuf, Bbuf, CE, eidx,
                                             W2, b2, W3, b3, out);
}

// Round 3
// 216.923 us; speedup vs baseline: 1.5238x; 1.3104x over previous
//
#include <hip/hip_runtime.h>

// Problem constants (fixed by harness)
#define NPG 96                  // nodes per graph
#define BGR 64                  // graphs
#define HID 64
#define INF 32
#define EF  16
#define DEG 8
#define NN  (BGR*NPG)           // 6144 nodes
#define NE  (BGR*NPG*DEG)       // 49152 edges
#define EPG (NPG*DEG)           // 768 edges per graph
#define PPG (NPG*NPG)           // 9216 pairs per graph

// ---------------------------------------------------------------------------
// K0: fold the activation-free encoder chains into single matrices.
//   WAa = W_atom@W_node@W1a  [32,64]   biasa = (b_atom@W_node+b_node)@W1a + b1
//   WAb = W_atom@W_node@W1b  [32,64]   biasb = (b_atom@W_node+b_node)@W1b
//   WEc = W_bond@W_edge@W1c  [16,64]   biasc = (b_bond@W_edge+b_edge)@W1c
// One block; ~0.6 M FMA.
// ---------------------------------------------------------------------------
__global__ __launch_bounds__(256) void precompute_kernel(
    const float* __restrict__ W_atom, const float* __restrict__ b_atom,
    const float* __restrict__ W_bond, const float* __restrict__ b_bond,
    const float* __restrict__ W_node, const float* __restrict__ b_node,
    const float* __restrict__ W_edge, const float* __restrict__ b_edge,
    const float* __restrict__ W1,     const float* __restrict__ b1,
    float* __restrict__ WAa, float* __restrict__ WAb,
    float* __restrict__ biasa, float* __restrict__ biasb,
    float* __restrict__ WEc, float* __restrict__ biasc)
{
    __shared__ float T[32*64];   // W_atom@W_node
    __shared__ float U[16*64];   // W_bond@W_edge
    __shared__ float bn[64], be[64];
    const int t = threadIdx.x;

    for (int idx = t; idx < 32*64; idx += 256) {
        const int r = idx >> 6, c = idx & 63;
        float s = 0.f;
        for (int k = 0; k < 64; ++k) s += W_atom[r*64+k] * W_node[k*64+c];
        T[idx] = s;
    }
    for (int idx = t; idx < 16*64; idx += 256) {
        const int r = idx >> 6, c = idx & 63;
        float s = 0.f;
        for (int k = 0; k < 64; ++k) s += W_bond[r*64+k] * W_edge[k*64+c];
        U[idx] = s;
    }
    if (t < 64) {
        float s = b_node[t];
        for (int k = 0; k < 64; ++k) s += b_atom[k] * W_node[k*64+t];
        bn[t] = s;
        float s2 = b_edge[t];
        for (int k = 0; k < 64; ++k) s2 += b_bond[k] * W_edge[k*64+t];
        be[t] = s2;
    }
    __syncthreads();

    for (int idx = t; idx < 32*64; idx += 256) {
        const int r = idx >> 6, c = idx & 63;
        float sa = 0.f, sb = 0.f;
        for (int k = 0; k < 64; ++k) {
            const float tv = T[r*64+k];
            sa += tv * W1[k*64+c];
            sb += tv * W1[(64+k)*64+c];
        }
        WAa[idx] = sa;  WAb[idx] = sb;
    }
    for (int idx = t; idx < 16*64; idx += 256) {
        const int r = idx >> 6, c = idx & 63;
        float s = 0.f;
        for (int k = 0; k < 64; ++k) s += U[r*64+k] * W1[(128+k)*64+c];
        WEc[idx] = s;
    }
    if (t < 64) {
        float sa = b1[t], sb = 0.f, sc = 0.f;
        for (int k = 0; k < 64; ++k) {
            sa += bn[k] * W1[k*64+t];
            sb += bn[k] * W1[(64+k)*64+t];
            sc += be[k] * W1[(128+k)*64+t];
        }
        biasa[t] = sa;  biasb[t] = sb;  biasc[t] = sc;
    }
}

// ---------------------------------------------------------------------------
// K1: per-node  A[n] = x[n]@WAa + biasa,  B[n] = x[n]@WAb + biasb.
// One node per wave; lane = channel. 128 FMA/thread.
// ---------------------------------------------------------------------------
__global__ __launch_bounds__(256) void node_kernel(
    const float* __restrict__ x,
    const float* __restrict__ WAa, const float* __restrict__ WAb,
    const float* __restrict__ biasa, const float* __restrict__ biasb,
    float* __restrict__ Abuf, float* __restrict__ Bbuf)
{
    const int wave = threadIdx.x >> 6, lane = threadIdx.x & 63;
    const int n = __builtin_amdgcn_readfirstlane(blockIdx.x * 4 + wave);
    const float* xr = x + n * INF;

    float a = biasa[lane], b = biasb[lane];
    #pragma unroll
    for (int k = 0; k < INF; ++k) {
        const float xk = xr[k];
        a += xk * WAa[k*HID + lane];
        b += xk * WAb[k*HID + lane];
    }
    Abuf[n*HID + lane] = a;
    Bbuf[n*HID + lane] = b;
}

// ---------------------------------------------------------------------------
// K2: dense pair MLP (no sparse term): out(i,j) = w3.relu(W2^T relu(A[i]+B[j]) + b2) + b3
// 256 consecutive pairs per block; B-rows staged in LDS.
// ---------------------------------------------------------------------------
__global__ __launch_bounds__(256, 5) void pair_dense_kernel(
    const float* __restrict__ Abuf, const float* __restrict__ Bbuf,
    const float* __restrict__ W2,   const float* __restrict__ b2,
    const float* __restrict__ W3,   const float* __restrict__ b3,
    float* __restrict__ out)
{
    __shared__ float sB[NPG * 65];
    __shared__ float sA[4 * 64];
    const int t  = threadIdx.x;
    const int p0 = blockIdx.x * 256;
    const int g  = p0 / PPG;
    const int l0 = p0 % PPG;
    const int i0 = l0 / NPG;

    const float* Bg = Bbuf + g * NPG * 64;
    for (int idx = t; idx < NPG*64; idx += 256)
        sB[(idx >> 6)*65 + (idx & 63)] = Bg[idx];
    {
        const int i = i0 + (t >> 6);
        sA[t] = (i < NPG) ? Abuf[(g*NPG + i)*64 + (t & 63)] : 0.f;
    }
    __syncthreads();

    const int l = l0 + t;
    const int i = l / NPG, j = l % NPG;
    const float* sArow = sA + (i - i0)*64;
    const float* sBrow = sB + j*65;

    float h2[64];
    #pragma unroll
    for (int c = 0; c < 64; ++c) h2[c] = b2[c];

    for (int k = 0; k < 64; ++k) {
        float h1 = sArow[k] + sBrow[k];
        h1 = fmaxf(h1, 0.f);
        const float4* wrow = (const float4*)(W2 + k*64);
        #pragma unroll
        for (int c4 = 0; c4 < 16; ++c4) {
            const float4 w = wrow[c4];
            h2[c4*4+0] += h1 * w.x;
            h2[c4*4+1] += h1 * w.y;
            h2[c4*4+2] += h1 * w.z;
            h2[c4*4+3] += h1 * w.w;
        }
    }

    float acc = b3[0];
    #pragma unroll
    for (int c = 0; c < 64; ++c) acc += fmaxf(h2[c], 0.f) * W3[c];
    out[p0 + t] = acc;
}

// ---------------------------------------------------------------------------
// K3: dedup edges per graph. One block per graph, one thread per edge.
// Linked-list dedup in LDS; chain owner sums raw edge_attr (16 floats,
// linearity!) and emits a compact record {key, cnt, sum_ea[16]} to global.
// ---------------------------------------------------------------------------
__global__ __launch_bounds__(EPG) void dedup_kernel(
    const float* __restrict__ ea,  const int* __restrict__ eidx,
    int* __restrict__ fkey, int* __restrict__ fcnt,
    float* __restrict__ fsea, int* __restrict__ gcount)
{
    __shared__ int   head[PPG];          // 36864 B
    __shared__ int   nxt[EPG];           //  3072 B
    __shared__ float sea[EPG * 17];      // 52224 B (stride 17 vs bank conflicts)
    __shared__ int   lcnt;
    const int t = threadIdx.x;
    const int g = blockIdx.x;

    for (int idx = t; idx < PPG; idx += EPG) head[idx] = -1;
    if (t == 0) lcnt = 0;
    const float* eag = ea + g * EPG * EF;
    for (int idx = t; idx < EPG*EF; idx += EPG)
        sea[(idx / EF)*17 + (idx % EF)] = eag[idx];

    const int u = eidx[g*EPG + t]      - g*NPG;
    const int v = eidx[NE + g*EPG + t] - g*NPG;
    const int key = u*NPG + v;
    __syncthreads();

    nxt[t] = atomicExch(&head[key], t);
    __syncthreads();

    if (head[key] == t) {
        float s[EF];
        #pragma unroll
        for (int q = 0; q < EF; ++q) s[q] = 0.f;
        int cnt = 0;
        for (int e = t; e != -1; e = nxt[e]) {
            ++cnt;
            #pragma unroll
            for (int q = 0; q < EF; ++q) s[q] += sea[e*17 + q];
        }
        const int pos  = atomicAdd(&lcnt, 1);
        const int slot = g*EPG + pos;
        fkey[slot] = key;
        fcnt[slot] = cnt;
        #pragma unroll
        for (int q = 0; q < EF; ++q) fsea[slot*EF + q] = s[q];
    }
    __syncthreads();
    if (t == 0) gcount[g] = lcnt;
}

// ---------------------------------------------------------------------------
// K4: re-run the MLP for distinct edge-pairs with the sparse term and
// overwrite out. Grid-wide: one thread per compact slot (192 blocks).
//   c[k] = sum_ea @ WEc[:,k] + cnt*biasc[k];  h1 = A[u]+B[v]+c
// ---------------------------------------------------------------------------
__global__ __launch_bounds__(256) void fixmlp_kernel(
    const float* __restrict__ Abuf, const float* __restrict__ Bbuf,
    const int* __restrict__ fkey, const int* __restrict__ fcnt,
    const float* __restrict__ fsea, const int* __restrict__ gcount,
    const float* __restrict__ WEc,  const float* __restrict__ biasc,
    const float* __restrict__ W2,   const float* __restrict__ b2,
    const float* __restrict__ W3,   const float* __restrict__ b3,
    float* __restrict__ out)
{
    const int s = blockIdx.x * 256 + threadIdx.x;
    const int g = s / EPG;
    const int l = s % EPG;
    if (l >= gcount[g]) return;

    const int key = fkey[s];
    const float cntf = (float)fcnt[s];
    const int u = key / NPG, v = key % NPG;

    float se[EF];
    {
        const float4* p = (const float4*)(fsea + s*EF);
        #pragma unroll
        for (int q4 = 0; q4 < 4; ++q4) {
            const float4 f = p[q4];
            se[q4*4+0] = f.x; se[q4*4+1] = f.y;
            se[q4*4+2] = f.z; se[q4*4+3] = f.w;
        }
    }

    const float* Ar = Abuf + (g*NPG + u)*64;
    const float* Br = Bbuf + (g*NPG + v)*64;

    float h2[64];
    #pragma unroll
    for (int c = 0; c < 64; ++c) h2[c] = b2[c];

    for (int k = 0; k < 64; ++k) {
        float ck = cntf * biasc[k];
        #pragma unroll
        for (int q = 0; q < EF; ++q) ck += se[q] * WEc[q*64 + k];
        float h1 = Ar[k] + Br[k] + ck;
        h1 = fmaxf(h1, 0.f);
        const float4* wrow = (const float4*)(W2 + k*64);
        #pragma unroll
        for (int c4 = 0; c4 < 16; ++c4) {
            const float4 w = wrow[c4];
            h2[c4*4+0] += h1 * w.x;
            h2[c4*4+1] += h1 * w.y;
            h2[c4*4+2] += h1 * w.z;
            h2[c4*4+3] += h1 * w.w;
        }
    }

    float acc = b3[0];
    #pragma unroll
    for (int c = 0; c < 64; ++c) acc += fmaxf(h2[c], 0.f) * W3[c];
    out[g*PPG + key] = acc;
}

// ---------------------------------------------------------------------------
extern "C" void kernel_launch(void* const* d_in, const int* in_sizes, int n_in,
                              void* d_out, int out_size, void* d_ws, size_t ws_size,
                              hipStream_t stream)
{
    const float* x      = (const float*)d_in[0];
    const float* ea     = (const float*)d_in[1];
    const int*   eidx   = (const int*)  d_in[2];
    // d_in[3]=idx0, d_in[4]=idx1, d_in[5]=n  -- derivable, unused
    const float* W_atom = (const float*)d_in[6];
    const float* b_atom = (const float*)d_in[7];
    const float* W_bond = (const float*)d_in[8];
    const float* b_bond = (const float*)d_in[9];
    const float* W_node = (const float*)d_in[10];
    const float* b_node = (const float*)d_in[11];
    const float* W_edge = (const float*)d_in[12];
    const float* b_edge = (const float*)d_in[13];
    const float* W1     = (const float*)d_in[14];
    const float* b1     = (const float*)d_in[15];
    const float* W2     = (const float*)d_in[16];
    const float* b2     = (const float*)d_in[17];
    const float* W3     = (const float*)d_in[18];
    const float* b3     = (const float*)d_in[19];
    float* out = (float*)d_out;

    float* ws    = (float*)d_ws;
    float* Abuf  = ws;                       // [NN,64]   393216
    float* Bbuf  = Abuf  + NN*HID;           // [NN,64]   393216
    float* WAa   = Bbuf  + NN*HID;           // [32,64]     2048
    float* WAb   = WAa   + 32*64;            // [32,64]     2048
    float* WEc   = WAb   + 32*64;            // [16,64]     1024
    float* biasa = WEc   + 16*64;            // [64]
    float* biasb = biasa + 64;               // [64]
    float* biasc = biasb + 64;               // [64]
    float* fsea  = biasc + 64;               // [NE,16]   786432
    int*   fkey  = (int*)(fsea + NE*EF);     // [NE]
    int*   fcnt  = fkey + NE;                // [NE]
    int*   gcount= fcnt + NE;                // [BGR]

    precompute_kernel<<<1, 256, 0, stream>>>(W_atom, b_atom, W_bond, b_bond,
                                             W_node, b_node, W_edge, b_edge,
                                             W1, b1, WAa, WAb, biasa, biasb,
                                             WEc, biasc);
    node_kernel<<<NN/4, 256, 0, stream>>>(x, WAa, WAb, biasa, biasb, Abuf, Bbuf);
    pair_dense_kernel<<<(BGR*PPG)/256, 256, 0, stream>>>(Abuf, Bbuf,
                                                         W2, b2, W3, b3, out);
    dedup_kernel<<<BGR, EPG, 0, stream>>>(ea, eidx, fkey, fcnt, fsea, gcount);
    fixmlp_kernel<<<NE/256, 256, 0, stream>>>(Abuf, Bbuf, fkey, fcnt, fsea,
                                              gcount, WEc, biasc,
                                              W2, b2, W3, b3, out);
}

// Round 4
// 184.487 us; speedup vs baseline: 1.7917x; 1.1758x over previous
//
#include <hip/hip_runtime.h>

// Problem constants (fixed by harness)
#define NPG 96                  // nodes per graph
#define BGR 64                  // graphs
#define HID 64
#define INF 32
#define EF  16
#define DEG 8
#define NN  (BGR*NPG)           // 6144 nodes
#define NE  (BGR*NPG*DEG)       // 49152 edges
#define EPG (NPG*DEG)           // 768 edges per graph
#define PPG (NPG*NPG)           // 9216 pairs per graph

typedef short bf16x8 __attribute__((ext_vector_type(8)));
typedef float f32x4  __attribute__((ext_vector_type(4)));

__device__ __forceinline__ unsigned rne2(float lo, float hi) {
    union { float f; unsigned u; } a, b; a.f = lo; b.f = hi;
    unsigned ua = a.u + 0x7FFF + ((a.u >> 16) & 1);
    unsigned ub = b.u + 0x7FFF + ((b.u >> 16) & 1);
    return (ua >> 16) | (ub & 0xFFFF0000u);
}
__device__ __forceinline__ unsigned short rne1(float x) {
    union { float f; unsigned u; } a; a.f = x;
    return (unsigned short)((a.u + 0x7FFF + ((a.u >> 16) & 1)) >> 16);
}

// ---------------------------------------------------------------------------
// K0: fold the activation-free encoder chains into single matrices.
// ---------------------------------------------------------------------------
__global__ __launch_bounds__(256) void precompute_kernel(
    const float* __restrict__ W_atom, const float* __restrict__ b_atom,
    const float* __restrict__ W_bond, const float* __restrict__ b_bond,
    const float* __restrict__ W_node, const float* __restrict__ b_node,
    const float* __restrict__ W_edge, const float* __restrict__ b_edge,
    const float* __restrict__ W1,     const float* __restrict__ b1,
    float* __restrict__ WAa, float* __restrict__ WAb,
    float* __restrict__ biasa, float* __restrict__ biasb,
    float* __restrict__ WEc, float* __restrict__ biasc)
{
    __shared__ float T[32*64];   // W_atom@W_node
    __shared__ float U[16*64];   // W_bond@W_edge
    __shared__ float bn[64], be[64];
    const int t = threadIdx.x;

    for (int idx = t; idx < 32*64; idx += 256) {
        const int r = idx >> 6, c = idx & 63;
        float s = 0.f;
        for (int k = 0; k < 64; ++k) s += W_atom[r*64+k] * W_node[k*64+c];
        T[idx] = s;
    }
    for (int idx = t; idx < 16*64; idx += 256) {
        const int r = idx >> 6, c = idx & 63;
        float s = 0.f;
        for (int k = 0; k < 64; ++k) s += W_bond[r*64+k] * W_edge[k*64+c];
        U[idx] = s;
    }
    if (t < 64) {
        float s = b_node[t];
        for (int k = 0; k < 64; ++k) s += b_atom[k] * W_node[k*64+t];
        bn[t] = s;
        float s2 = b_edge[t];
        for (int k = 0; k < 64; ++k) s2 += b_bond[k] * W_edge[k*64+t];
        be[t] = s2;
    }
    __syncthreads();

    for (int idx = t; idx < 32*64; idx += 256) {
        const int r = idx >> 6, c = idx & 63;
        float sa = 0.f, sb = 0.f;
        for (int k = 0; k < 64; ++k) {
            const float tv = T[r*64+k];
            sa += tv * W1[k*64+c];
            sb += tv * W1[(64+k)*64+c];
        }
        WAa[idx] = sa;  WAb[idx] = sb;
    }
    for (int idx = t; idx < 16*64; idx += 256) {
        const int r = idx >> 6, c = idx & 63;
        float s = 0.f;
        for (int k = 0; k < 64; ++k) s += U[r*64+k] * W1[(128+k)*64+c];
        WEc[idx] = s;
    }
    if (t < 64) {
        float sa = b1[t], sb = 0.f, sc = 0.f;
        for (int k = 0; k < 64; ++k) {
            sa += bn[k] * W1[k*64+t];
            sb += bn[k] * W1[(64+k)*64+t];
            sc += be[k] * W1[(128+k)*64+t];
        }
        biasa[t] = sa;  biasb[t] = sb;  biasc[t] = sc;
    }
}

// ---------------------------------------------------------------------------
// K1: per-node  A[n] = x[n]@WAa + biasa,  B[n] = x[n]@WAb + biasb.
// ---------------------------------------------------------------------------
__global__ __launch_bounds__(256) void node_kernel(
    const float* __restrict__ x,
    const float* __restrict__ WAa, const float* __restrict__ WAb,
    const float* __restrict__ biasa, const float* __restrict__ biasb,
    float* __restrict__ Abuf, float* __restrict__ Bbuf)
{
    const int wave = threadIdx.x >> 6, lane = threadIdx.x & 63;
    const int n = __builtin_amdgcn_readfirstlane(blockIdx.x * 4 + wave);
    const float* xr = x + n * INF;

    float a = biasa[lane], b = biasb[lane];
    #pragma unroll
    for (int k = 0; k < INF; ++k) {
        const float xk = xr[k];
        a += xk * WAa[k*HID + lane];
        b += xk * WAb[k*HID + lane];
    }
    Abuf[n*HID + lane] = a;
    Bbuf[n*HID + lane] = b;
}

// ---------------------------------------------------------------------------
// K2: dense pair MLP on MFMA.
//   out(i,j) = w3 . relu( relu(A[i]+B[j]) @ W2_bf16 + b2 ) + b3
// Block = (graph, 8 i-rows). Wave w owns i = i0+2w, i0+2w+1; per i, 6 groups
// of 16 consecutive j. Each group: 2 bf16 h1 A-frags (built fp32+RNE) ×
// 4 N-tiles of W2 -> 8 mfma_f32_16x16x32_bf16. Epilogue fp32 in regs +
// shfl_xor reduction; lane col==0 stores float4 (4 consecutive j).
// Edge-pairs get wrong values here; K4 overwrites them in full fp32.
// ---------------------------------------------------------------------------
#define SBST 68                 // sB row stride (floats): 16B-aligned, 2-way banks
#define W2ST 72                 // sW2t row stride (ushorts): 16B-aligned
__global__ __launch_bounds__(256) void pair_dense_kernel(
    const float* __restrict__ Abuf, const float* __restrict__ Bbuf,
    const float* __restrict__ W2,   const float* __restrict__ b2,
    const float* __restrict__ W3,   const float* __restrict__ b3,
    float* __restrict__ out)
{
    __shared__ float sB[NPG * SBST];              // 26112 B
    __shared__ float sA[8 * 64];                  //  2048 B
    __shared__ unsigned short sW2t[64 * W2ST];    //  9216 B  (W2^T in bf16)
    const int t  = threadIdx.x;
    const int g  = blockIdx.x / 12;
    const int i0 = (blockIdx.x % 12) * 8;

    // ---- stage ----
    const float* Bg = Bbuf + g * NPG * 64;
    for (int idx = t; idx < NPG*64; idx += 256)
        sB[(idx >> 6)*SBST + (idx & 63)] = Bg[idx];
    for (int idx = t; idx < 8*64; idx += 256)
        sA[idx] = Abuf[(g*NPG + i0 + (idx >> 6))*64 + (idx & 63)];
    for (int idx = t; idx < 64*64; idx += 256) {
        const int k = idx >> 6, n = idx & 63;
        sW2t[n*W2ST + k] = rne1(W2[idx]);     // transpose: [n][k]
    }
    __syncthreads();

    const int wave = t >> 6, lane = t & 63;
    const int col = lane & 15, q = lane >> 4;

    // ---- per-wave constants ----
    bf16x8 w2f[4][2];                    // [ntile][kchunk]
    #pragma unroll
    for (int nt = 0; nt < 4; ++nt)
        #pragma unroll
        for (int c = 0; c < 2; ++c)
            w2f[nt][c] = *(const bf16x8*)(sW2t + (nt*16 + col)*W2ST + c*32 + q*8);

    float w3l[4], b2l[4];
    #pragma unroll
    for (int nt = 0; nt < 4; ++nt) {
        w3l[nt] = W3[nt*16 + col];
        b2l[nt] = b2[nt*16 + col];
    }
    const float b3v = b3[0];

    #pragma unroll
    for (int ii = 0; ii < 2; ++ii) {
        const int il = wave*2 + ii;          // local i in [0,8)
        // A-row cache: k = c*32 + q*8 + jj
        float areg[16];
        {
            const float4* Ar = (const float4*)(sA + il*64 + q*8);
            const float4 a0 = Ar[0], a1 = Ar[1];       // k: q*8 .. q*8+7
            const float4 a2 = Ar[8], a3 = Ar[9];       // k: 32+q*8 ..
            areg[0]=a0.x; areg[1]=a0.y; areg[2]=a0.z; areg[3]=a0.w;
            areg[4]=a1.x; areg[5]=a1.y; areg[6]=a1.z; areg[7]=a1.w;
            areg[8]=a2.x; areg[9]=a2.y; areg[10]=a2.z; areg[11]=a2.w;
            areg[12]=a3.x; areg[13]=a3.y; areg[14]=a3.z; areg[15]=a3.w;
        }
        float* outr = out + g*PPG + (i0 + il)*NPG;

        for (int jc = 0; jc < 6; ++jc) {
            const int j0 = jc * 16;
            // ---- build h1 bf16 frags (m = col -> pair (i, j0+col)) ----
            union { bf16x8 v; unsigned u[4]; } h1[2];
            const float* Brow = sB + (j0 + col)*SBST + q*8;
            #pragma unroll
            for (int c = 0; c < 2; ++c) {
                const float4 b0 = *(const float4*)(Brow + c*32);
                const float4 b1v = *(const float4*)(Brow + c*32 + 4);
                float h[8];
                h[0] = fmaxf(areg[c*8+0] + b0.x, 0.f);
                h[1] = fmaxf(areg[c*8+1] + b0.y, 0.f);
                h[2] = fmaxf(areg[c*8+2] + b0.z, 0.f);
                h[3] = fmaxf(areg[c*8+3] + b0.w, 0.f);
                h[4] = fmaxf(areg[c*8+4] + b1v.x, 0.f);
                h[5] = fmaxf(areg[c*8+5] + b1v.y, 0.f);
                h[6] = fmaxf(areg[c*8+6] + b1v.z, 0.f);
                h[7] = fmaxf(areg[c*8+7] + b1v.w, 0.f);
                #pragma unroll
                for (int p2 = 0; p2 < 4; ++p2)
                    h1[c].u[p2] = rne2(h[2*p2], h[2*p2+1]);
            }
            // ---- 8 MFMAs ----
            f32x4 acc[4];
            #pragma unroll
            for (int nt = 0; nt < 4; ++nt) {
                f32x4 z = {0.f, 0.f, 0.f, 0.f};
                z = __builtin_amdgcn_mfma_f32_16x16x32_bf16(h1[0].v, w2f[nt][0], z, 0, 0, 0);
                z = __builtin_amdgcn_mfma_f32_16x16x32_bf16(h1[1].v, w2f[nt][1], z, 0, 0, 0);
                acc[nt] = z;
            }
            // ---- epilogue: relu(h2+b2).w3, reduce over 16 lanes ----
            float p[4];
            #pragma unroll
            for (int r = 0; r < 4; ++r) {
                float s = 0.f;
                #pragma unroll
                for (int nt = 0; nt < 4; ++nt)
                    s += fmaxf(acc[nt][r] + b2l[nt], 0.f) * w3l[nt];
                p[r] = s;
            }
            #pragma unroll
            for (int off = 1; off < 16; off <<= 1) {
                #pragma unroll
                for (int r = 0; r < 4; ++r)
                    p[r] += __shfl_xor(p[r], off, 64);
            }
            if (col == 0) {
                float4 o = make_float4(p[0]+b3v, p[1]+b3v, p[2]+b3v, p[3]+b3v);
                *(float4*)(outr + j0 + q*4) = o;   // rows q*4..q*4+3 of group
            }
        }
    }
}

// ---------------------------------------------------------------------------
// K3: dedup edges per graph; chain owner sums raw edge_attr (linearity).
// ---------------------------------------------------------------------------
__global__ __launch_bounds__(EPG) void dedup_kernel(
    const float* __restrict__ ea,  const int* __restrict__ eidx,
    int* __restrict__ fkey, int* __restrict__ fcnt,
    float* __restrict__ fsea, int* __restrict__ gcount)
{
    __shared__ int   head[PPG];          // 36864 B
    __shared__ int   nxt[EPG];           //  3072 B
    __shared__ float sea[EPG * 17];      // 52224 B
    __shared__ int   lcnt;
    const int t = threadIdx.x;
    const int g = blockIdx.x;

    for (int idx = t; idx < PPG; idx += EPG) head[idx] = -1;
    if (t == 0) lcnt = 0;
    const float* eag = ea + g * EPG * EF;
    for (int idx = t; idx < EPG*EF; idx += EPG)
        sea[(idx / EF)*17 + (idx % EF)] = eag[idx];

    const int u = eidx[g*EPG + t]      - g*NPG;
    const int v = eidx[NE + g*EPG + t] - g*NPG;
    const int key = u*NPG + v;
    __syncthreads();

    nxt[t] = atomicExch(&head[key], t);
    __syncthreads();

    if (head[key] == t) {
        float s[EF];
        #pragma unroll
        for (int q = 0; q < EF; ++q) s[q] = 0.f;
        int cnt = 0;
        for (int e = t; e != -1; e = nxt[e]) {
            ++cnt;
            #pragma unroll
            for (int q = 0; q < EF; ++q) s[q] += sea[e*17 + q];
        }
        const int pos  = atomicAdd(&lcnt, 1);
        const int slot = g*EPG + pos;
        fkey[slot] = key;
        fcnt[slot] = cnt;
        #pragma unroll
        for (int q = 0; q < EF; ++q) fsea[slot*EF + q] = s[q];
    }
    __syncthreads();
    if (t == 0) gcount[g] = lcnt;
}

// ---------------------------------------------------------------------------
// K4: fp32 re-run of the MLP for distinct edge-pairs (sparse term included),
// overwrites out. One thread per compact slot.
// ---------------------------------------------------------------------------
__global__ __launch_bounds__(256) void fixmlp_kernel(
    const float* __restrict__ Abuf, const float* __restrict__ Bbuf,
    const int* __restrict__ fkey, const int* __restrict__ fcnt,
    const float* __restrict__ fsea, const int* __restrict__ gcount,
    const float* __restrict__ WEc,  const float* __restrict__ biasc,
    const float* __restrict__ W2,   const float* __restrict__ b2,
    const float* __restrict__ W3,   const float* __restrict__ b3,
    float* __restrict__ out)
{
    const int s = blockIdx.x * 256 + threadIdx.x;
    const int g = s / EPG;
    const int l = s % EPG;
    if (l >= gcount[g]) return;

    const int key = fkey[s];
    const float cntf = (float)fcnt[s];
    const int u = key / NPG, v = key % NPG;

    float se[EF];
    {
        const float4* p = (const float4*)(fsea + s*EF);
        #pragma unroll
        for (int q4 = 0; q4 < 4; ++q4) {
            const float4 f = p[q4];
            se[q4*4+0] = f.x; se[q4*4+1] = f.y;
            se[q4*4+2] = f.z; se[q4*4+3] = f.w;
        }
    }

    const float* Ar = Abuf + (g*NPG + u)*64;
    const float* Br = Bbuf + (g*NPG + v)*64;

    float h2[64];
    #pragma unroll
    for (int c = 0; c < 64; ++c) h2[c] = b2[c];

    for (int k = 0; k < 64; ++k) {
        float ck = cntf * biasc[k];
        #pragma unroll
        for (int q = 0; q < EF; ++q) ck += se[q] * WEc[q*64 + k];
        float h1 = Ar[k] + Br[k] + ck;
        h1 = fmaxf(h1, 0.f);
        const float4* wrow = (const float4*)(W2 + k*64);
        #pragma unroll
        for (int c4 = 0; c4 < 16; ++c4) {
            const float4 w = wrow[c4];
            h2[c4*4+0] += h1 * w.x;
            h2[c4*4+1] += h1 * w.y;
            h2[c4*4+2] += h1 * w.z;
            h2[c4*4+3] += h1 * w.w;
        }
    }

    float acc = b3[0];
    #pragma unroll
    for (int c = 0; c < 64; ++c) acc += fmaxf(h2[c], 0.f) * W3[c];
    out[g*PPG + key] = acc;
}

// ---------------------------------------------------------------------------
extern "C" void kernel_launch(void* const* d_in, const int* in_sizes, int n_in,
                              void* d_out, int out_size, void* d_ws, size_t ws_size,
                              hipStream_t stream)
{
    const float* x      = (const float*)d_in[0];
    const float* ea     = (const float*)d_in[1];
    const int*   eidx   = (const int*)  d_in[2];
    // d_in[3]=idx0, d_in[4]=idx1, d_in[5]=n  -- derivable, unused
    const float* W_atom = (const float*)d_in[6];
    const float* b_atom = (const float*)d_in[7];
    const float* W_bond = (const float*)d_in[8];
    const float* b_bond = (const float*)d_in[9];
    const float* W_node = (const float*)d_in[10];
    const float* b_node = (const float*)d_in[11];
    const float* W_edge = (const float*)d_in[12];
    const float* b_edge = (const float*)d_in[13];
    const float* W1     = (const float*)d_in[14];
    const float* b1     = (const float*)d_in[15];
    const float* W2     = (const float*)d_in[16];
    const float* b2     = (const float*)d_in[17];
    const float* W3     = (const float*)d_in[18];
    const float* b3     = (const float*)d_in[19];
    float* out = (float*)d_out;

    float* ws    = (float*)d_ws;
    float* Abuf  = ws;                       // [NN,64]
    float* Bbuf  = Abuf  + NN*HID;           // [NN,64]
    float* WAa   = Bbuf  + NN*HID;           // [32,64]
    float* WAb   = WAa   + 32*64;            // [32,64]
    float* WEc   = WAb   + 32*64;            // [16,64]
    float* biasa = WEc   + 16*64;            // [64]
    float* biasb = biasa + 64;               // [64]
    float* biasc = biasb + 64;               // [64]
    float* fsea  = biasc + 64;               // [NE,16]
    int*   fkey  = (int*)(fsea + NE*EF);     // [NE]
    int*   fcnt  = fkey + NE;                // [NE]
    int*   gcount= fcnt + NE;                // [BGR]

    precompute_kernel<<<1, 256, 0, stream>>>(W_atom, b_atom, W_bond, b_bond,
                                             W_node, b_node, W_edge, b_edge,
                                             W1, b1, WAa, WAb, biasa, biasb,
                                             WEc, biasc);
    node_kernel<<<NN/4, 256, 0, stream>>>(x, WAa, WAb, biasa, biasb, Abuf, Bbuf);
    pair_dense_kernel<<<BGR*12, 256, 0, stream>>>(Abuf, Bbuf,
                                                  W2, b2, W3, b3, out);
    dedup_kernel<<<BGR, EPG, 0, stream>>>(ea, eidx, fkey, fcnt, fsea, gcount);
    fixmlp_kernel<<<NE/256, 256, 0, stream>>>(Abuf, Bbuf, fkey, fcnt, fsea,
                                              gcount, WEc, biasc,
                                              W2, b2, W3, b3, out);
}

// Round 5
// 169.522 us; speedup vs baseline: 1.9499x; 1.0883x over previous
//
#include <hip/hip_runtime.h>

// Problem constants (fixed by harness)
#define NPG 96                  // nodes per graph
#define BGR 64                  // graphs
#define HID 64
#define INF 32
#define EF  16
#define DEG 8
#define NN  (BGR*NPG)           // 6144 nodes
#define NE  (BGR*NPG*DEG)       // 49152 edges
#define EPG (NPG*DEG)           // 768 edges per graph
#define PPG (NPG*NPG)           // 9216 pairs per graph

typedef short bf16x8 __attribute__((ext_vector_type(8)));
typedef float f32x4  __attribute__((ext_vector_type(4)));

__device__ __forceinline__ unsigned rne2(float lo, float hi) {
    union { float f; unsigned u; } a, b; a.f = lo; b.f = hi;
    unsigned ua = a.u + 0x7FFF + ((a.u >> 16) & 1);
    unsigned ub = b.u + 0x7FFF + ((b.u >> 16) & 1);
    return (ua >> 16) | (ub & 0xFFFF0000u);
}
__device__ __forceinline__ unsigned short rne1(float x) {
    union { float f; unsigned u; } a; a.f = x;
    return (unsigned short)((a.u + 0x7FFF + ((a.u >> 16) & 1)) >> 16);
}

// ---------------------------------------------------------------------------
// K1: per-node chain (no precompute dependency):
//   xh = x@W_atom + b_atom;  en = xh@W_node + b_node
//   A[n] = en@W1[0:64] + b1   (b1 folded),   B[n] = en@W1[64:128]
// One node per wave; lane = channel.
// ---------------------------------------------------------------------------
__global__ __launch_bounds__(256) void node_kernel(
    const float* __restrict__ x,
    const float* __restrict__ W_atom, const float* __restrict__ b_atom,
    const float* __restrict__ W_node, const float* __restrict__ b_node,
    const float* __restrict__ W1,     const float* __restrict__ b1,
    float* __restrict__ Abuf, float* __restrict__ Bbuf)
{
    __shared__ float sh[4][64];
    const int wave = threadIdx.x >> 6, lane = threadIdx.x & 63;
    const int n = __builtin_amdgcn_readfirstlane(blockIdx.x * 4 + wave);
    const float* xr = x + n * INF;

    float xh = b_atom[lane];
    #pragma unroll
    for (int k = 0; k < INF; ++k) xh += xr[k] * W_atom[k*HID + lane];
    sh[wave][lane] = xh;
    __syncthreads();

    float en = b_node[lane];
    #pragma unroll
    for (int k = 0; k < HID; ++k) en += sh[wave][k] * W_node[k*HID + lane];
    __syncthreads();
    sh[wave][lane] = en;
    __syncthreads();

    float a = b1[lane], b = 0.f;
    #pragma unroll
    for (int k = 0; k < HID; ++k) {
        const float ek = sh[wave][k];
        a += ek * W1[k*HID + lane];
        b += ek * W1[(HID + k)*HID + lane];
    }
    Abuf[n*HID + lane] = a;
    Bbuf[n*HID + lane] = b;
}

// ---------------------------------------------------------------------------
// K2: dense pair MLP on MFMA.
//   out(i,j) = w3 . relu( relu(A[i]+B[j]) @ W2_bf16 + b2 ) + b3
// Block = (graph, 8 i-rows). Wave w owns i = i0+2w, i0+2w+1; per i, 6 groups
// of 16 consecutive j -> 8x mfma_f32_16x16x32_bf16 per group. Epilogue fp32
// + shfl_xor reduction. Edge-pairs get overwritten by K4 in full fp32.
// ---------------------------------------------------------------------------
#define SBST 68                 // sB row stride (floats)
#define W2ST 72                 // sW2t row stride (ushorts)
__global__ __launch_bounds__(256) void pair_dense_kernel(
    const float* __restrict__ Abuf, const float* __restrict__ Bbuf,
    const float* __restrict__ W2,   const float* __restrict__ b2,
    const float* __restrict__ W3,   const float* __restrict__ b3,
    float* __restrict__ out)
{
    __shared__ float sB[NPG * SBST];              // 26112 B
    __shared__ float sA[8 * 64];                  //  2048 B
    __shared__ unsigned short sW2t[64 * W2ST];    //  9216 B  (W2^T in bf16)
    const int t  = threadIdx.x;
    const int g  = blockIdx.x / 12;
    const int i0 = (blockIdx.x % 12) * 8;

    const float* Bg = Bbuf + g * NPG * 64;
    for (int idx = t; idx < NPG*64; idx += 256)
        sB[(idx >> 6)*SBST + (idx & 63)] = Bg[idx];
    for (int idx = t; idx < 8*64; idx += 256)
        sA[idx] = Abuf[(g*NPG + i0 + (idx >> 6))*64 + (idx & 63)];
    for (int idx = t; idx < 64*64; idx += 256) {
        const int k = idx >> 6, n = idx & 63;
        sW2t[n*W2ST + k] = rne1(W2[idx]);     // transpose: [n][k]
    }
    __syncthreads();

    const int wave = t >> 6, lane = t & 63;
    const int col = lane & 15, q = lane >> 4;

    bf16x8 w2f[4][2];
    #pragma unroll
    for (int nt = 0; nt < 4; ++nt)
        #pragma unroll
        for (int c = 0; c < 2; ++c)
            w2f[nt][c] = *(const bf16x8*)(sW2t + (nt*16 + col)*W2ST + c*32 + q*8);

    float w3l[4], b2l[4];
    #pragma unroll
    for (int nt = 0; nt < 4; ++nt) {
        w3l[nt] = W3[nt*16 + col];
        b2l[nt] = b2[nt*16 + col];
    }
    const float b3v = b3[0];

    #pragma unroll
    for (int ii = 0; ii < 2; ++ii) {
        const int il = wave*2 + ii;
        float areg[16];
        {
            const float4* Ar = (const float4*)(sA + il*64 + q*8);
            const float4 a0 = Ar[0], a1 = Ar[1];
            const float4 a2 = Ar[8], a3 = Ar[9];
            areg[0]=a0.x; areg[1]=a0.y; areg[2]=a0.z; areg[3]=a0.w;
            areg[4]=a1.x; areg[5]=a1.y; areg[6]=a1.z; areg[7]=a1.w;
            areg[8]=a2.x; areg[9]=a2.y; areg[10]=a2.z; areg[11]=a2.w;
            areg[12]=a3.x; areg[13]=a3.y; areg[14]=a3.z; areg[15]=a3.w;
        }
        float* outr = out + g*PPG + (i0 + il)*NPG;

        for (int jc = 0; jc < 6; ++jc) {
            const int j0 = jc * 16;
            union { bf16x8 v; unsigned u[4]; } h1[2];
            const float* Brow = sB + (j0 + col)*SBST + q*8;
            #pragma unroll
            for (int c = 0; c < 2; ++c) {
                const float4 b0 = *(const float4*)(Brow + c*32);
                const float4 b1v = *(const float4*)(Brow + c*32 + 4);
                float h[8];
                h[0] = fmaxf(areg[c*8+0] + b0.x, 0.f);
                h[1] = fmaxf(areg[c*8+1] + b0.y, 0.f);
                h[2] = fmaxf(areg[c*8+2] + b0.z, 0.f);
                h[3] = fmaxf(areg[c*8+3] + b0.w, 0.f);
                h[4] = fmaxf(areg[c*8+4] + b1v.x, 0.f);
                h[5] = fmaxf(areg[c*8+5] + b1v.y, 0.f);
                h[6] = fmaxf(areg[c*8+6] + b1v.z, 0.f);
                h[7] = fmaxf(areg[c*8+7] + b1v.w, 0.f);
                #pragma unroll
                for (int p2 = 0; p2 < 4; ++p2)
                    h1[c].u[p2] = rne2(h[2*p2], h[2*p2+1]);
            }
            f32x4 acc[4];
            #pragma unroll
            for (int nt = 0; nt < 4; ++nt) {
                f32x4 z = {0.f, 0.f, 0.f, 0.f};
                z = __builtin_amdgcn_mfma_f32_16x16x32_bf16(h1[0].v, w2f[nt][0], z, 0, 0, 0);
                z = __builtin_amdgcn_mfma_f32_16x16x32_bf16(h1[1].v, w2f[nt][1], z, 0, 0, 0);
                acc[nt] = z;
            }
            float p[4];
            #pragma unroll
            for (int r = 0; r < 4; ++r) {
                float s = 0.f;
                #pragma unroll
                for (int nt = 0; nt < 4; ++nt)
                    s += fmaxf(acc[nt][r] + b2l[nt], 0.f) * w3l[nt];
                p[r] = s;
            }
            #pragma unroll
            for (int off = 1; off < 16; off <<= 1) {
                #pragma unroll
                for (int r = 0; r < 4; ++r)
                    p[r] += __shfl_xor(p[r], off, 64);
            }
            if (col == 0) {
                float4 o = make_float4(p[0]+b3v, p[1]+b3v, p[2]+b3v, p[3]+b3v);
                *(float4*)(outr + j0 + q*4) = o;
            }
        }
    }
}

// ---------------------------------------------------------------------------
// K3: dedup edges per graph (slim LDS: 40 KB). One block/graph, one
// thread/edge. Chain owner sums raw edge_attr straight from L2 (linearity)
// and emits compact {key, cnt, sum_ea[16]}.
// ---------------------------------------------------------------------------
__global__ __launch_bounds__(EPG) void dedup_kernel(
    const float* __restrict__ ea,  const int* __restrict__ eidx,
    int* __restrict__ fkey, int* __restrict__ fcnt,
    float* __restrict__ fsea, int* __restrict__ gcount)
{
    __shared__ int head[PPG];          // 36864 B
    __shared__ int nxt[EPG];           //  3072 B
    __shared__ int lcnt;
    const int t = threadIdx.x;
    const int g = blockIdx.x;

    for (int idx = t; idx < PPG; idx += EPG) head[idx] = -1;
    if (t == 0) lcnt = 0;

    const int u = eidx[g*EPG + t]      - g*NPG;
    const int v = eidx[NE + g*EPG + t] - g*NPG;
    const int key = u*NPG + v;
    __syncthreads();

    nxt[t] = atomicExch(&head[key], t);
    __syncthreads();

    if (head[key] == t) {
        const float* eag = ea + (size_t)g * EPG * EF;
        float s[EF];
        #pragma unroll
        for (int q = 0; q < EF; ++q) s[q] = 0.f;
        int cnt = 0;
        for (int e = t; e != -1; e = nxt[e]) {
            ++cnt;
            const float4* p = (const float4*)(eag + e*EF);
            #pragma unroll
            for (int q4 = 0; q4 < 4; ++q4) {
                const float4 f = p[q4];
                s[q4*4+0] += f.x; s[q4*4+1] += f.y;
                s[q4*4+2] += f.z; s[q4*4+3] += f.w;
            }
        }
        const int pos  = atomicAdd(&lcnt, 1);
        const int slot = g*EPG + pos;
        fkey[slot] = key;
        fcnt[slot] = cnt;
        #pragma unroll
        for (int q = 0; q < EF; ++q) fsea[slot*EF + q] = s[q];
    }
    __syncthreads();
    if (t == 0) gcount[g] = lcnt;
}

// ---------------------------------------------------------------------------
// K4: fp32 re-run of the MLP for distinct edge-pairs, overwrites out.
// WEc = W_bond@W_edge@W1[128:192] and biasc folded per-block (131k FMA,
// cheap) -- removes the precompute kernel + its serial dependency.
// ---------------------------------------------------------------------------
__global__ __launch_bounds__(256) void fixmlp_kernel(
    const float* __restrict__ Abuf, const float* __restrict__ Bbuf,
    const int* __restrict__ fkey, const int* __restrict__ fcnt,
    const float* __restrict__ fsea, const int* __restrict__ gcount,
    const float* __restrict__ W_bond, const float* __restrict__ b_bond,
    const float* __restrict__ W_edge, const float* __restrict__ b_edge,
    const float* __restrict__ W1,
    const float* __restrict__ W2,   const float* __restrict__ b2,
    const float* __restrict__ W3,   const float* __restrict__ b3,
    float* __restrict__ out)
{
    __shared__ float U[16*64];      // W_bond@W_edge
    __shared__ float sWEc[16*64];   // U@W1c
    __shared__ float sbc[64];       // biasc
    const int t = threadIdx.x;

    for (int idx = t; idx < 16*64; idx += 256) {
        const int r = idx >> 6, c = idx & 63;
        float s = 0.f;
        for (int k = 0; k < 64; ++k) s += W_bond[r*64+k] * W_edge[k*64+c];
        U[idx] = s;
    }
    if (t < 64) {
        float s2 = b_edge[t];
        for (int k = 0; k < 64; ++k) s2 += b_bond[k] * W_edge[k*64+t];
        sbc[t] = s2;   // temp: be
    }
    __syncthreads();
    for (int idx = t; idx < 16*64; idx += 256) {
        const int r = idx >> 6, c = idx & 63;
        float s = 0.f;
        for (int k = 0; k < 64; ++k) s += U[r*64+k] * W1[(128+k)*64+c];
        sWEc[idx] = s;
    }
    __syncthreads();
    if (t < 64) {
        float sc = 0.f;
        for (int k = 0; k < 64; ++k) sc += sbc[k] * W1[(128+k)*64+t];
        __syncthreads();           // all lanes done reading sbc as 'be'
        sbc[t] = sc;               // now biasc
    } else {
        __syncthreads();
    }
    __syncthreads();

    const int s = blockIdx.x * 256 + t;
    const int g = s / EPG;
    const int l = s % EPG;
    if (l >= gcount[g]) return;

    const int key = fkey[s];
    const float cntf = (float)fcnt[s];
    const int u = key / NPG, v = key % NPG;

    float se[EF];
    {
        const float4* p = (const float4*)(fsea + s*EF);
        #pragma unroll
        for (int q4 = 0; q4 < 4; ++q4) {
            const float4 f = p[q4];
            se[q4*4+0] = f.x; se[q4*4+1] = f.y;
            se[q4*4+2] = f.z; se[q4*4+3] = f.w;
        }
    }

    const float* Ar = Abuf + (g*NPG + u)*64;
    const float* Br = Bbuf + (g*NPG + v)*64;

    float h2[64];
    #pragma unroll
    for (int c = 0; c < 64; ++c) h2[c] = b2[c];

    for (int k = 0; k < 64; ++k) {
        float ck = cntf * sbc[k];
        #pragma unroll
        for (int q = 0; q < EF; ++q) ck += se[q] * sWEc[q*64 + k];
        float h1 = Ar[k] + Br[k] + ck;
        h1 = fmaxf(h1, 0.f);
        const float4* wrow = (const float4*)(W2 + k*64);
        #pragma unroll
        for (int c4 = 0; c4 < 16; ++c4) {
            const float4 w = wrow[c4];
            h2[c4*4+0] += h1 * w.x;
            h2[c4*4+1] += h1 * w.y;
            h2[c4*4+2] += h1 * w.z;
            h2[c4*4+3] += h1 * w.w;
        }
    }

    float acc = b3[0];
    #pragma unroll
    for (int c = 0; c < 64; ++c) acc += fmaxf(h2[c], 0.f) * W3[c];
    out[g*PPG + key] = acc;
}

// ---------------------------------------------------------------------------
extern "C" void kernel_launch(void* const* d_in, const int* in_sizes, int n_in,
                              void* d_out, int out_size, void* d_ws, size_t ws_size,
                              hipStream_t stream)
{
    const float* x      = (const float*)d_in[0];
    const float* ea     = (const float*)d_in[1];
    const int*   eidx   = (const int*)  d_in[2];
    // d_in[3]=idx0, d_in[4]=idx1, d_in[5]=n  -- derivable, unused
    const float* W_atom = (const float*)d_in[6];
    const float* b_atom = (const float*)d_in[7];
    const float* W_bond = (const float*)d_in[8];
    const float* b_bond = (const float*)d_in[9];
    const float* W_node = (const float*)d_in[10];
    const float* b_node = (const float*)d_in[11];
    const float* W_edge = (const float*)d_in[12];
    const float* b_edge = (const float*)d_in[13];
    const float* W1     = (const float*)d_in[14];
    const float* b1     = (const float*)d_in[15];
    const float* W2     = (const float*)d_in[16];
    const float* b2     = (const float*)d_in[17];
    const float* W3     = (const float*)d_in[18];
    const float* b3     = (const float*)d_in[19];
    float* out = (float*)d_out;

    float* ws    = (float*)d_ws;
    float* Abuf  = ws;                       // [NN,64]
    float* Bbuf  = Abuf  + NN*HID;           // [NN,64]
    float* fsea  = Bbuf  + NN*HID;           // [NE,16]
    int*   fkey  = (int*)(fsea + NE*EF);     // [NE]
    int*   fcnt  = fkey + NE;                // [NE]
    int*   gcount= fcnt + NE;                // [BGR]

    node_kernel<<<NN/4, 256, 0, stream>>>(x, W_atom, b_atom, W_node, b_node,
                                          W1, b1, Abuf, Bbuf);
    dedup_kernel<<<BGR, EPG, 0, stream>>>(ea, eidx, fkey, fcnt, fsea, gcount);
    pair_dense_kernel<<<BGR*12, 256, 0, stream>>>(Abuf, Bbuf,
                                                  W2, b2, W3, b3, out);
    fixmlp_kernel<<<NE/256, 256, 0, stream>>>(Abuf, Bbuf, fkey, fcnt, fsea,
                                              gcount, W_bond, b_bond,
                                              W_edge, b_edge, W1,
                                              W2, b2, W3, b3, out);
}